// Round 16
// baseline (957.097 us; speedup 1.0000x reference)
//
#include <hip/hip_runtime.h>
#include <hip/hip_bf16.h>
#include <stdint.h>

typedef float f32x4 __attribute__((ext_vector_type(4)));
typedef float f32x16 __attribute__((ext_vector_type(16)));
typedef int i32x4 __attribute__((ext_vector_type(4)));
typedef int i32x8 __attribute__((ext_vector_type(8)));
typedef long i64;

#define BM 128
#define BN 128
#define BKB 64   // K elements (=bytes, fp8) per tile step

// swizzle: 16B-chunk slot = chunk ^ swz(row). Period 16 in row -> the 32-row
// fragment read has exactly 2 rows per (parity,slot) class = free 2-way.
__device__ __host__ __forceinline__ int swz(int r) {
  return ((r >> 1) ^ (r >> 3)) & 3;
}

// ---------------- pre-quant: fp32 (bf16-valued) -> fp8 e4m3fn, LINEAR -------
__global__ __launch_bounds__(256) void quant_fp8_from_f32(
    const float* __restrict__ in, const float* __restrict__ scale,
    uint8_t* __restrict__ out, int n16) {
  const int i = blockIdx.x * blockDim.x + threadIdx.x;
  if (i >= n16) return;
  const float inv_s = 1.0f / scale[0];
  const float* p = in + (i64)i * 16;
  f32x4 v[4];
  v[0] = *(const f32x4*)p;
  v[1] = *(const f32x4*)(p + 4);
  v[2] = *(const f32x4*)(p + 8);
  v[3] = *(const f32x4*)(p + 12);
  uint32_t w[4];
#pragma unroll
  for (int q = 0; q < 4; q++) {
    float f0 = fminf(fmaxf(v[q][0] * inv_s, -448.f), 448.f);
    float f1 = fminf(fmaxf(v[q][1] * inv_s, -448.f), 448.f);
    float f2 = fminf(fmaxf(v[q][2] * inv_s, -448.f), 448.f);
    float f3 = fminf(fmaxf(v[q][3] * inv_s, -448.f), 448.f);
    int r = 0;
    r = __builtin_amdgcn_cvt_pk_fp8_f32(f0, f1, r, false);
    r = __builtin_amdgcn_cvt_pk_fp8_f32(f2, f3, r, true);
    w[q] = (uint32_t)r;
  }
  ((uint4*)out)[i] = make_uint4(w[0], w[1], w[2], w[3]);
}

// ---------------- async global->LDS, 16B per lane ----------------
__device__ __forceinline__ void gload_lds16(const void* g, void* l) {
  __builtin_amdgcn_global_load_lds(
      (const __attribute__((address_space(1))) uint32_t*)g,
      (__attribute__((address_space(3))) uint32_t*)l, 16, 0, 0);
}

// round f32 to bf16 (RNE), return as f32 value
__device__ __forceinline__ float bf16_rne_f32(float f) {
  union { float f; uint32_t u; } c; c.f = f;
  uint32_t lsb = (c.u >> 16) & 1u;
  c.u += 0x7FFFu + lsb;
  c.u &= 0xFFFF0000u;
  return c.f;
}

// ---------------- fp8 GEMM via MX-scaled 32x32x64 MFMA (scales = 1.0) -------
// 128x128 tile, 4 waves (2x2 of 64x64), 2x2 of 32x32x64 mfma_scale per wave.
// Double-buffered LDS (2x16KB), ONE barrier per K-step: issue next tile's
// global_load_lds, then ds_read+MFMA current tile, then barrier (implicit
// vmcnt(0)+lgkmcnt(0) drain) -> loads hide under MFMA.
__global__ __launch_bounds__(256) void gemm_fp8_mx(
    const uint8_t* __restrict__ Aq, const uint8_t* __restrict__ Bq,
    const float* __restrict__ bias,
    const float* __restrict__ xs, const float* __restrict__ wsc,
    float* __restrict__ C, int M, int N, int K) {
  __shared__ uint8_t sA[2][BM * BKB];
  __shared__ uint8_t sB[2][BN * BKB];

  const int nbn = N / BN;
  int bid = blockIdx.x;
  { int cpx = gridDim.x >> 3; bid = (bid & 7) * cpx + (bid >> 3); }  // XCD swizzle
  const int bm = bid / nbn;
  const int bn = bid % nbn;

  const int t = threadIdx.x, lane = t & 63, wave = t >> 6;
  const int wm = (wave >> 1) * 64;
  const int wn = (wave & 1) * 64;
  const int g = lane >> 5;          // K-half group (0: k0-31, 1: k32-63)
  const int r31 = lane & 31;

  f32x16 acc[2][2];
#pragma unroll
  for (int i = 0; i < 2; i++)
#pragma unroll
    for (int j = 0; j < 2; j++) acc[i][j] = (f32x16)0.f;

  // ---- staging: thread t stages 16B chunk (t&3) of rows t/4 and t/4+64 ----
  const int srow = t >> 2;
  const int c16 = t & 3;
  i64 src0, src1;
  {
    const int r0 = srow, r1 = srow + 64;
    src0 = (i64)r0 * K + ((c16 ^ swz(r0)) << 4);
    src1 = (i64)r1 * K + ((c16 ^ swz(r1)) << 4);
  }
  const uint8_t* gA = Aq + (i64)(bm * BM) * K;
  const uint8_t* gB = Bq + (i64)(bn * BN) * K;

  // ---- fragment read offsets (hoisted): [frag][16B half], + buf*8192 ----
  int aoff[2][2], boff[2][2];
#pragma unroll
  for (int i = 0; i < 2; i++) {
    const int ra = wm + i * 32 + r31;
    const int sa_ = swz(ra);
    aoff[i][0] = ra * 64 + (((2 * g + 0) ^ sa_) << 4);
    aoff[i][1] = ra * 64 + (((2 * g + 1) ^ sa_) << 4);
    const int rb = wn + i * 32 + r31;
    const int sb_ = swz(rb);
    boff[i][0] = rb * 64 + (((2 * g + 0) ^ sb_) << 4);
    boff[i][1] = rb * 64 + (((2 * g + 1) ^ sb_) << 4);
  }

  const int NT = K / BKB;
  // prologue: stage tile 0 into buffer 0
  gload_lds16(gA + src0, &sA[0][t * 16]);
  gload_lds16(gA + src1, &sA[0][t * 16 + 4096]);
  gload_lds16(gB + src0, &sB[0][t * 16]);
  gload_lds16(gB + src1, &sB[0][t * 16 + 4096]);
  __syncthreads();

  int cur = 0;
  for (int it = 0; it < NT; ++it) {
    // issue next tile's loads into the other buffer (hidden under MFMA)
    if (it + 1 < NT) {
      const i64 kt = (i64)(it + 1) * BKB;
      const int nxt = cur ^ 1;
      gload_lds16(gA + src0 + kt, &sA[nxt][t * 16]);
      gload_lds16(gA + src1 + kt, &sA[nxt][t * 16 + 4096]);
      gload_lds16(gB + src0 + kt, &sB[nxt][t * 16]);
      gload_lds16(gB + src1 + kt, &sB[nxt][t * 16 + 4096]);
    }

    union { i32x4 h[2]; i32x8 v; } ua[2], ub[2];
#pragma unroll
    for (int i = 0; i < 2; i++) {
      ua[i].h[0] = *(const i32x4*)(&sA[cur][0] + aoff[i][0]);
      ua[i].h[1] = *(const i32x4*)(&sA[cur][0] + aoff[i][1]);
      ub[i].h[0] = *(const i32x4*)(&sB[cur][0] + boff[i][0]);
      ub[i].h[1] = *(const i32x4*)(&sB[cur][0] + boff[i][1]);
    }
#pragma unroll
    for (int i = 0; i < 2; i++)
#pragma unroll
      for (int j = 0; j < 2; j++)
        acc[i][j] = __builtin_amdgcn_mfma_scale_f32_32x32x64_f8f6f4(
            ua[i].v, ub[j].v, acc[i][j],
            0, 0,          // cbsz=fp8(e4m3), blgp=fp8(e4m3)
            0, 127,        // scale_a = e8m0 1.0
            0, 127);       // scale_b = e8m0 1.0

    __syncthreads();   // drains vmcnt (next tile staged) + lgkm; one/K-step
    cur ^= 1;
  }

  // ---- epilogue: bf16_rne(acc*(sx*sw) + bias) stored as FP32 -------------
  // 32x32 C/D layout (m74/m101): col = lane&31, row = (reg&3)+8*(reg>>2)+4*g
  const float sc = xs[0] * wsc[0];
#pragma unroll
  for (int j = 0; j < 2; j++) {
    const int col = bn * BN + wn + j * 32 + r31;
    const float bv = bias[col];
#pragma unroll
    for (int i = 0; i < 2; i++) {
      const int rowbase = bm * BM + wm + i * 32 + 4 * g;
#pragma unroll
      for (int reg = 0; reg < 16; reg++) {
        const int row = rowbase + (reg & 3) + 8 * (reg >> 2);
        C[(i64)row * N + col] = bf16_rne_f32(acc[i][j][reg] * sc + bv);
      }
    }
  }
}

extern "C" void kernel_launch(void* const* d_in, const int* in_sizes, int n_in,
                              void* d_out, int out_size, void* d_ws, size_t ws_size,
                              hipStream_t stream) {
  // Verified I/O model (R11 oracle + R12-R15 passes): declared order, element
  // counts, ALL buffers fp32-stored bf16-valued, output fp32.
  const float* x = (const float*)d_in[0];
  const float* w = (const float*)d_in[1];
  const float* bias = (const float*)d_in[2];
  const float* x_scale = (const float*)d_in[3];
  const float* w_scale = (const float*)d_in[4];

  const int N = in_sizes[2];
  const int K = in_sizes[1] / N;
  const int M = in_sizes[0] / K;

  uint8_t* xq = (uint8_t*)d_ws;                     // M*K = 32 MB
  uint8_t* wq = (uint8_t*)d_ws + (size_t)M * K;     // N*K = 64 MB

  {
    const int n16 = (M * K) / 16;
    quant_fp8_from_f32<<<(n16 + 255) / 256, 256, 0, stream>>>(x, x_scale, xq, n16);
  }
  {
    const int n16 = (int)(((i64)N * K) / 16);
    quant_fp8_from_f32<<<(n16 + 255) / 256, 256, 0, stream>>>(w, w_scale, wq, n16);
  }

  dim3 grid((M / BM) * (N / BN));
  gemm_fp8_mx<<<grid, 256, 0, stream>>>(
      xq, wq, bias, x_scale, w_scale, (float*)d_out, M, N, K);
}

// Round 17
// 804.745 us; speedup vs baseline: 1.1893x; 1.1893x over previous
//
#include <hip/hip_runtime.h>
#include <hip/hip_bf16.h>
#include <stdint.h>

typedef float f32x4 __attribute__((ext_vector_type(4)));
typedef float f32x16 __attribute__((ext_vector_type(16)));
typedef int i32x4 __attribute__((ext_vector_type(4)));
typedef int i32x8 __attribute__((ext_vector_type(8)));
typedef long i64;

#define BM 256
#define BN 256
#define BKB 64   // K elements (=bytes, fp8) per tile step

// 16B-chunk slot = chunk ^ swz(row); period 16 covers the 32-row frag read.
__device__ __host__ __forceinline__ int swz(int r) {
  return ((r >> 1) ^ (r >> 3)) & 3;
}

// ---------------- pre-quant: fp32 (bf16-valued) -> fp8 e4m3fn, LINEAR -------
__global__ __launch_bounds__(256) void quant_fp8_from_f32(
    const float* __restrict__ in, const float* __restrict__ scale,
    uint8_t* __restrict__ out, int n16) {
  const int i = blockIdx.x * blockDim.x + threadIdx.x;
  if (i >= n16) return;
  const float inv_s = 1.0f / scale[0];
  const float* p = in + (i64)i * 16;
  f32x4 v[4];
  v[0] = *(const f32x4*)p;
  v[1] = *(const f32x4*)(p + 4);
  v[2] = *(const f32x4*)(p + 8);
  v[3] = *(const f32x4*)(p + 12);
  uint32_t w[4];
#pragma unroll
  for (int q = 0; q < 4; q++) {
    float f0 = fminf(fmaxf(v[q][0] * inv_s, -448.f), 448.f);
    float f1 = fminf(fmaxf(v[q][1] * inv_s, -448.f), 448.f);
    float f2 = fminf(fmaxf(v[q][2] * inv_s, -448.f), 448.f);
    float f3 = fminf(fmaxf(v[q][3] * inv_s, -448.f), 448.f);
    int r = 0;
    r = __builtin_amdgcn_cvt_pk_fp8_f32(f0, f1, r, false);
    r = __builtin_amdgcn_cvt_pk_fp8_f32(f2, f3, r, true);
    w[q] = (uint32_t)r;
  }
  ((uint4*)out)[i] = make_uint4(w[0], w[1], w[2], w[3]);
}

__device__ __forceinline__ void gload_lds16(const void* g, void* l) {
  __builtin_amdgcn_global_load_lds(
      (const __attribute__((address_space(1))) uint32_t*)g,
      (__attribute__((address_space(3))) uint32_t*)l, 16, 0, 0);
}

__device__ __forceinline__ float bf16_rne_f32(float f) {
  union { float f; uint32_t u; } c; c.f = f;
  uint32_t lsb = (c.u >> 16) & 1u;
  c.u += 0x7FFFu + lsb;
  c.u &= 0xFFFF0000u;
  return c.f;
}

// ---------------- fp8 GEMM via MX-scaled 32x32x64 MFMA (scales = 1.0) -------
// 256x256 tile, 8 waves (2x4), wave-tile 128x64 (4 A-frags x 2 B-frags = 8
// MFMA per K-step, 12 b128 reads -> 1.5 reads/MFMA vs 2.0 at 128^2: the LDS
// pipe was the R15/16 bottleneck). Double-buffered LDS (64KB), one barrier
// per K-step; staging issued before ds_read+MFMA so the ~250cy L2 latency
// hides under ~560cy of compute.
__global__ __launch_bounds__(512, 2) void gemm_fp8_mx(
    const uint8_t* __restrict__ Aq, const uint8_t* __restrict__ Bq,
    const float* __restrict__ bias,
    const float* __restrict__ xs, const float* __restrict__ wsc,
    float* __restrict__ C, int M, int N, int K) {
  __shared__ uint8_t sA[2][BM * BKB];   // 2 x 16 KB
  __shared__ uint8_t sB[2][BN * BKB];   // 2 x 16 KB

  const int nbn = N / BN;
  int bid = blockIdx.x;
  { int cpx = gridDim.x >> 3; bid = (bid & 7) * cpx + (bid >> 3); }  // XCD swizzle
  const int bm = bid / nbn;
  const int bn = bid % nbn;

  const int t = threadIdx.x, lane = t & 63, wave = t >> 6;
  const int wm = (wave >> 2) * 128;   // 2 wave-rows of 128
  const int wn = (wave & 3) * 64;     // 4 wave-cols of 64
  const int g = lane >> 5;            // K-half group
  const int r31 = lane & 31;

  f32x16 acc[4][2];
#pragma unroll
  for (int i = 0; i < 4; i++)
#pragma unroll
    for (int j = 0; j < 2; j++) acc[i][j] = (f32x16)0.f;

  // ---- staging: thread t stages chunk (t&3) of rows t/4 and t/4+128 ----
  const int srow = t >> 2;            // 0..127
  const int c16 = t & 3;
  const i64 src0 = (i64)srow * K + ((c16 ^ swz(srow)) << 4);
  const i64 src1 = (i64)(srow + 128) * K + ((c16 ^ swz(srow + 128)) << 4);
  const uint8_t* gA = Aq + (i64)(bm * BM) * K;
  const uint8_t* gB = Bq + (i64)(bn * BN) * K;

  // ---- fragment read offsets (hoisted) ----
  int aoff[4][2], boff[2][2];
#pragma unroll
  for (int i = 0; i < 4; i++) {
    const int ra = wm + i * 32 + r31;
    const int sa_ = swz(ra);
    aoff[i][0] = ra * 64 + (((2 * g + 0) ^ sa_) << 4);
    aoff[i][1] = ra * 64 + (((2 * g + 1) ^ sa_) << 4);
  }
#pragma unroll
  for (int j = 0; j < 2; j++) {
    const int rb = wn + j * 32 + r31;
    const int sb_ = swz(rb);
    boff[j][0] = rb * 64 + (((2 * g + 0) ^ sb_) << 4);
    boff[j][1] = rb * 64 + (((2 * g + 1) ^ sb_) << 4);
  }

  const int NT = K / BKB;
  // prologue: stage tile 0 into buffer 0
  gload_lds16(gA + src0, &sA[0][t * 16]);
  gload_lds16(gA + src1, &sA[0][t * 16 + 8192]);
  gload_lds16(gB + src0, &sB[0][t * 16]);
  gload_lds16(gB + src1, &sB[0][t * 16 + 8192]);
  __syncthreads();

  int cur = 0;
  for (int it = 0; it < NT; ++it) {
    if (it + 1 < NT) {      // prefetch next tile (lands during MFMA below)
      const i64 kt = (i64)(it + 1) * BKB;
      const int nxt = cur ^ 1;
      gload_lds16(gA + src0 + kt, &sA[nxt][t * 16]);
      gload_lds16(gA + src1 + kt, &sA[nxt][t * 16 + 8192]);
      gload_lds16(gB + src0 + kt, &sB[nxt][t * 16]);
      gload_lds16(gB + src1 + kt, &sB[nxt][t * 16 + 8192]);
    }

    union { i32x4 h[2]; i32x8 v; } ua[4], ub[2];
#pragma unroll
    for (int i = 0; i < 4; i++) {
      ua[i].h[0] = *(const i32x4*)(&sA[cur][0] + aoff[i][0]);
      ua[i].h[1] = *(const i32x4*)(&sA[cur][0] + aoff[i][1]);
    }
#pragma unroll
    for (int j = 0; j < 2; j++) {
      ub[j].h[0] = *(const i32x4*)(&sB[cur][0] + boff[j][0]);
      ub[j].h[1] = *(const i32x4*)(&sB[cur][0] + boff[j][1]);
    }
#pragma unroll
    for (int i = 0; i < 4; i++)
#pragma unroll
      for (int j = 0; j < 2; j++)
        acc[i][j] = __builtin_amdgcn_mfma_scale_f32_32x32x64_f8f6f4(
            ua[i].v, ub[j].v, acc[i][j],
            0, 0,          // cbsz=fp8(e4m3), blgp=fp8(e4m3)
            0, 127,        // scale_a = e8m0 1.0
            0, 127);       // scale_b = e8m0 1.0

    __syncthreads();   // drains vmcnt (next tile staged) once per K-step
    cur ^= 1;
  }

  // ---- epilogue: bf16_rne(acc*(sx*sw) + bias) stored as FP32 -------------
  // 32x32 C/D layout (m74/m101): col = lane&31, row = (reg&3)+8*(reg>>2)+4*g
  const float sc = xs[0] * wsc[0];
#pragma unroll
  for (int j = 0; j < 2; j++) {
    const int col = bn * BN + wn + j * 32 + r31;
    const float bv = bias[col];
#pragma unroll
    for (int i = 0; i < 4; i++) {
      const int rowbase = bm * BM + wm + i * 32 + 4 * g;
#pragma unroll
      for (int reg = 0; reg < 16; reg++) {
        const int row = rowbase + (reg & 3) + 8 * (reg >> 2);
        C[(i64)row * N + col] = bf16_rne_f32(acc[i][j][reg] * sc + bv);
      }
    }
  }
}

extern "C" void kernel_launch(void* const* d_in, const int* in_sizes, int n_in,
                              void* d_out, int out_size, void* d_ws, size_t ws_size,
                              hipStream_t stream) {
  // Verified I/O model (R11 oracle + R12-R16 passes): declared order, element
  // counts, ALL buffers fp32-stored bf16-valued, output fp32.
  const float* x = (const float*)d_in[0];
  const float* w = (const float*)d_in[1];
  const float* bias = (const float*)d_in[2];
  const float* x_scale = (const float*)d_in[3];
  const float* w_scale = (const float*)d_in[4];

  const int N = in_sizes[2];
  const int K = in_sizes[1] / N;
  const int M = in_sizes[0] / K;

  uint8_t* xq = (uint8_t*)d_ws;                     // M*K = 32 MB
  uint8_t* wq = (uint8_t*)d_ws + (size_t)M * K;     // N*K = 64 MB

  {
    const int n16 = (M * K) / 16;
    quant_fp8_from_f32<<<(n16 + 255) / 256, 256, 0, stream>>>(x, x_scale, xq, n16);
  }
  {
    const int n16 = (int)(((i64)N * K) / 16);
    quant_fp8_from_f32<<<(n16 + 255) / 256, 256, 0, stream>>>(w, w_scale, wq, n16);
  }

  dim3 grid((M / BM) * (N / BN));
  gemm_fp8_mx<<<grid, 512, 0, stream>>>(
      xq, wq, bias, x_scale, w_scale, (float*)d_out, M, N, K);
}

// Round 19
// 793.960 us; speedup vs baseline: 1.2055x; 1.0136x over previous
//
#include <hip/hip_runtime.h>
#include <hip/hip_bf16.h>
#include <stdint.h>

typedef float f32x4 __attribute__((ext_vector_type(4)));
typedef float f32x16 __attribute__((ext_vector_type(16)));
typedef int i32x4 __attribute__((ext_vector_type(4)));
typedef int i32x8 __attribute__((ext_vector_type(8)));
typedef long i64;

#define BM 256
#define BN 256
#define BKB 64   // K elements (=bytes, fp8) per tile step

// 16B-chunk slot = chunk ^ swz(row); period 16 covers the 32-row frag read.
__device__ __host__ __forceinline__ int swz(int r) {
  return ((r >> 1) ^ (r >> 3)) & 3;
}

// ---------------- pre-quant: fp32 (bf16-valued) -> fp8 e4m3fn, LINEAR -------
__global__ __launch_bounds__(256) void quant_fp8_from_f32(
    const float* __restrict__ in, const float* __restrict__ scale,
    uint8_t* __restrict__ out, int n16) {
  const int i = blockIdx.x * blockDim.x + threadIdx.x;
  if (i >= n16) return;
  const float inv_s = 1.0f / scale[0];
  const float* p = in + (i64)i * 16;
  f32x4 v[4];
  v[0] = *(const f32x4*)p;
  v[1] = *(const f32x4*)(p + 4);
  v[2] = *(const f32x4*)(p + 8);
  v[3] = *(const f32x4*)(p + 12);
  uint32_t w[4];
#pragma unroll
  for (int q = 0; q < 4; q++) {
    float f0 = fminf(fmaxf(v[q][0] * inv_s, -448.f), 448.f);
    float f1 = fminf(fmaxf(v[q][1] * inv_s, -448.f), 448.f);
    float f2 = fminf(fmaxf(v[q][2] * inv_s, -448.f), 448.f);
    float f3 = fminf(fmaxf(v[q][3] * inv_s, -448.f), 448.f);
    int r = 0;
    r = __builtin_amdgcn_cvt_pk_fp8_f32(f0, f1, r, false);
    r = __builtin_amdgcn_cvt_pk_fp8_f32(f2, f3, r, true);
    w[q] = (uint32_t)r;
  }
  ((uint4*)out)[i] = make_uint4(w[0], w[1], w[2], w[3]);
}

__device__ __forceinline__ void gload_lds16(const void* g, void* l) {
  __builtin_amdgcn_global_load_lds(
      (const __attribute__((address_space(1))) uint32_t*)g,
      (__attribute__((address_space(3))) uint32_t*)l, 16, 0, 0);
}

__device__ __forceinline__ float bf16_rne_f32(float f) {
  union { float f; uint32_t u; } c; c.f = f;
  uint32_t lsb = (c.u >> 16) & 1u;
  c.u += 0x7FFFu + lsb;
  c.u &= 0xFFFF0000u;
  return c.f;
}

// ---------------- fp8 GEMM via MX-scaled 32x32x64 MFMA (scales = 1.0) -------
// 256x256 tile, 8 waves (2x4), wave-tile 128x64. Double-buffered LDS (64KB),
// counted-vmcnt pipeline (T4): per K-step issue next tile's 4 global_load_lds
// PER THREAD, then s_waitcnt vmcnt(4) (drain the 4 oldest = CURRENT tile;
// keep the 4 newest in flight across the barrier), raw s_barrier, ds_read +
// MFMA, raw s_barrier. [R18 bug: vmcnt(8) counted per-wave halves, but vmcnt
// is per-THREAD instructions = 4/iter -> vmcnt(8) was a no-op -> NaN race.]
__global__ __launch_bounds__(512, 2) void gemm_fp8_mx(
    const uint8_t* __restrict__ Aq, const uint8_t* __restrict__ Bq,
    const float* __restrict__ bias,
    const float* __restrict__ xs, const float* __restrict__ wsc,
    float* __restrict__ C, int M, int N, int K) {
  __shared__ uint8_t sA[2][BM * BKB];   // 2 x 16 KB
  __shared__ uint8_t sB[2][BN * BKB];   // 2 x 16 KB

  const int nbn = N / BN;
  int bid = blockIdx.x;
  { int cpx = gridDim.x >> 3; bid = (bid & 7) * cpx + (bid >> 3); }  // XCD swizzle
  const int bm = bid / nbn;
  const int bn = bid % nbn;

  const int t = threadIdx.x, lane = t & 63, wave = t >> 6;
  const int wm = (wave >> 2) * 128;   // 2 wave-rows of 128
  const int wn = (wave & 3) * 64;     // 4 wave-cols of 64
  const int g = lane >> 5;            // K-half group
  const int r31 = lane & 31;

  f32x16 acc[4][2];
#pragma unroll
  for (int i = 0; i < 4; i++)
#pragma unroll
    for (int j = 0; j < 2; j++) acc[i][j] = (f32x16)0.f;

  // ---- staging: thread t stages chunk (t&3) of rows t/4 and t/4+128 ----
  const int srow = t >> 2;            // 0..127
  const int c16 = t & 3;
  const i64 src0 = (i64)srow * K + ((c16 ^ swz(srow)) << 4);
  const i64 src1 = (i64)(srow + 128) * K + ((c16 ^ swz(srow + 128)) << 4);
  const uint8_t* gA = Aq + (i64)(bm * BM) * K;
  const uint8_t* gB = Bq + (i64)(bn * BN) * K;

  // ---- fragment read offsets (hoisted) ----
  int aoff[4][2], boff[2][2];
#pragma unroll
  for (int i = 0; i < 4; i++) {
    const int ra = wm + i * 32 + r31;
    const int sa_ = swz(ra);
    aoff[i][0] = ra * 64 + (((2 * g + 0) ^ sa_) << 4);
    aoff[i][1] = ra * 64 + (((2 * g + 1) ^ sa_) << 4);
  }
#pragma unroll
  for (int j = 0; j < 2; j++) {
    const int rb = wn + j * 32 + r31;
    const int sb_ = swz(rb);
    boff[j][0] = rb * 64 + (((2 * g + 0) ^ sb_) << 4);
    boff[j][1] = rb * 64 + (((2 * g + 1) ^ sb_) << 4);
  }

  const int NT = K / BKB;
  // prologue: stage tile 0 into buffer 0 (4 loads in flight; counted below)
  gload_lds16(gA + src0, &sA[0][t * 16]);
  gload_lds16(gA + src1, &sA[0][t * 16 + 8192]);
  gload_lds16(gB + src0, &sB[0][t * 16]);
  gload_lds16(gB + src1, &sB[0][t * 16 + 8192]);

  int cur = 0;
  for (int it = 0; it < NT; ++it) {
    if (it + 1 < NT) {
      // issue next tile's 4 loads; they stay in flight across the barrier
      const i64 kt = (i64)(it + 1) * BKB;
      const int nxt = cur ^ 1;
      gload_lds16(gA + src0 + kt, &sA[nxt][t * 16]);
      gload_lds16(gA + src1 + kt, &sA[nxt][t * 16 + 8192]);
      gload_lds16(gB + src0 + kt, &sB[nxt][t * 16]);
      gload_lds16(gB + src1 + kt, &sB[nxt][t * 16 + 8192]);
      asm volatile("s_waitcnt vmcnt(4)" ::: "memory");   // current tile landed
    } else {
      asm volatile("s_waitcnt vmcnt(0)" ::: "memory");   // final tile landed
    }
    __builtin_amdgcn_s_barrier();   // raw: no implicit vmcnt drain

    union { i32x4 h[2]; i32x8 v; } ua[4], ub[2];
#pragma unroll
    for (int i = 0; i < 4; i++) {
      ua[i].h[0] = *(const i32x4*)(&sA[cur][0] + aoff[i][0]);
      ua[i].h[1] = *(const i32x4*)(&sA[cur][0] + aoff[i][1]);
    }
#pragma unroll
    for (int j = 0; j < 2; j++) {
      ub[j].h[0] = *(const i32x4*)(&sB[cur][0] + boff[j][0]);
      ub[j].h[1] = *(const i32x4*)(&sB[cur][0] + boff[j][1]);
    }
#pragma unroll
    for (int i = 0; i < 4; i++)
#pragma unroll
      for (int j = 0; j < 2; j++)
        acc[i][j] = __builtin_amdgcn_mfma_scale_f32_32x32x64_f8f6f4(
            ua[i].v, ub[j].v, acc[i][j],
            0, 0,          // cbsz=fp8(e4m3), blgp=fp8(e4m3)
            0, 127,        // scale_a = e8m0 1.0
            0, 127);       // scale_b = e8m0 1.0

    // reads of buf cur are register-consumed (compiler lgkmcnt before MFMA)
    // before this barrier; after it, next iter may overwrite buf cur.
    __builtin_amdgcn_s_barrier();
    cur ^= 1;
  }

  // ---- epilogue: bf16_rne(acc*(sx*sw) + bias) stored as FP32 -------------
  // 32x32 C/D layout (m74/m101): col = lane&31, row = (reg&3)+8*(reg>>2)+4*g
  const float sc = xs[0] * wsc[0];
#pragma unroll
  for (int j = 0; j < 2; j++) {
    const int col = bn * BN + wn + j * 32 + r31;
    const float bv = bias[col];
#pragma unroll
    for (int i = 0; i < 4; i++) {
      const int rowbase = bm * BM + wm + i * 32 + 4 * g;
#pragma unroll
      for (int reg = 0; reg < 16; reg++) {
        const int row = rowbase + (reg & 3) + 8 * (reg >> 2);
        C[(i64)row * N + col] = bf16_rne_f32(acc[i][j][reg] * sc + bv);
      }
    }
  }
}

extern "C" void kernel_launch(void* const* d_in, const int* in_sizes, int n_in,
                              void* d_out, int out_size, void* d_ws, size_t ws_size,
                              hipStream_t stream) {
  // Verified I/O model (R11 oracle + R12-R17 passes): declared order, element
  // counts, ALL buffers fp32-stored bf16-valued, output fp32.
  const float* x = (const float*)d_in[0];
  const float* w = (const float*)d_in[1];
  const float* bias = (const float*)d_in[2];
  const float* x_scale = (const float*)d_in[3];
  const float* w_scale = (const float*)d_in[4];

  const int N = in_sizes[2];
  const int K = in_sizes[1] / N;
  const int M = in_sizes[0] / K;

  uint8_t* xq = (uint8_t*)d_ws;                     // M*K = 32 MB
  uint8_t* wq = (uint8_t*)d_ws + (size_t)M * K;     // N*K = 64 MB

  {
    const int n16 = (M * K) / 16;
    quant_fp8_from_f32<<<(n16 + 255) / 256, 256, 0, stream>>>(x, x_scale, xq, n16);
  }
  {
    const int n16 = (int)(((i64)N * K) / 16);
    quant_fp8_from_f32<<<(n16 + 255) / 256, 256, 0, stream>>>(w, w_scale, wq, n16);
  }

  dim3 grid((M / BM) * (N / BN));
  gemm_fp8_mx<<<grid, 512, 0, stream>>>(
      xq, wq, bias, x_scale, w_scale, (float*)d_out, M, N, K);
}